// Round 5
// baseline (651.693 us; speedup 1.0000x reference)
//
#include <hip/hip_runtime.h>

typedef unsigned short u16;
typedef unsigned int u32;
typedef __attribute__((ext_vector_type(8))) short s16x8;   // 8 bf16 (4 VGPRs)
typedef __attribute__((ext_vector_type(4))) float f32x4;

__device__ __forceinline__ float bf2f(u16 u) { return __uint_as_float(((u32)u) << 16); }
__device__ __forceinline__ u16 f2bf(float f) {
    u32 b = __float_as_uint(f);
    b += 0x7fffu + ((b >> 16) & 1u);
    return (u16)(b >> 16);
}
// lane 0-15 -> x, 16-31 -> y, 32-47 -> z, 48-63 -> w  (head = lane>>4)
__device__ __forceinline__ float pick_head(float4 a, int lane) {
    float lo = (lane & 16) ? a.y : a.x;
    float hi = (lane & 16) ? a.w : a.z;
    return (lane & 32) ? hi : lo;
}
// select one of 5 registers by rel (0..4) — cndmask chain, no scratch
__device__ __forceinline__ float sel5(float a0, float a1, float a2, float a3, float a4, int rel) {
    float x01 = (rel == 0) ? a0 : a1;
    float x23 = (rel == 2) ? a2 : a3;
    float x = (rel < 2) ? x01 : x23;
    return (rel == 4) ? a4 : x;
}

__global__ void probe_mark(float* __restrict__ out, int n, float val) {
    int i = blockIdx.x * blockDim.x + threadIdx.x;
    if (i < n) out[i] = val;
}

// ---------------- small prep ----------------
__global__ void zero_fill(u32* __restrict__ p, int n) {
    int i = blockIdx.x * blockDim.x + threadIdx.x;
    if (i < n) p[i] = 0u;
}

// wt[(w*256+c)*128+k] = bf16( w<5 ? Ws[w][k][c] : W_res[k][c] )   (W^T, bf16)
__global__ void cvt_weights(const float* __restrict__ Ws, const float* __restrict__ W_res,
                            u16* __restrict__ wt) {
    int i = blockIdx.x * blockDim.x + threadIdx.x;
    if (i >= 6 * 256 * 128) return;
    int k = i & 127;
    int c = (i >> 7) & 255;
    int w = i >> 15;
    float v = (w < 5) ? Ws[(size_t)w * 32768 + k * 256 + c] : W_res[k * 256 + c];
    wt[i] = f2bf(v);
}

// w_d_all[k][rel*4+h] = sum_c W[k][h*64+c]*att_dst[rel][h][c]
// w_s_cat[rel][k][h]  = sum_c W[k][h*64+c]*att_src[rel][h][c]
__global__ void prep_kernel(const float* __restrict__ Ws, const float* __restrict__ att_src,
                            const float* __restrict__ att_dst, const float* __restrict__ biases,
                            float* __restrict__ w_d_all, float* __restrict__ w_s_cat,
                            float* __restrict__ bias_sum) {
    int b = blockIdx.x;
    if (b < 5) {
        int k = threadIdx.x;
        if (k >= 128) return;
        const float* Wr = Ws + (size_t)b * 128 * 256 + (size_t)k * 256;
        for (int h = 0; h < 4; ++h) {
            float ss = 0.f, sd = 0.f;
            for (int c = 0; c < 64; ++c) {
                float w = Wr[h * 64 + c];
                ss += w * att_src[(b * 4 + h) * 64 + c];
                sd += w * att_dst[(b * 4 + h) * 64 + c];
            }
            w_d_all[k * 20 + b * 4 + h] = sd;
            w_s_cat[b * 512 + k * 4 + h] = ss;
        }
    } else if (threadIdx.x < 256) {
        float s = 0.f;
        for (int r = 0; r < 5; ++r) s += biases[r * 256 + threadIdx.x];
        bias_sum[threadIdx.x] = s;
    }
}

// ---------------- merged skinny GEMMs (a_s / a_d projections) ----------------
struct SDesc { const float* A; const float* W; float* out; int N; int Kout; int start; };
struct STab { SDesc d[6]; int total; };

__global__ void skinny_all(STab T) {
    int idx = blockIdx.x * blockDim.x + threadIdx.x;
    if (idx >= T.total) return;
    int mi = 0;
#pragma unroll
    for (int i = 1; i < 6; ++i) if (idx >= T.d[i].start) mi = i;
    SDesc d = T.d[mi];
    int local = idx - d.start;
    int row = local / d.Kout, col = local - row * d.Kout;
    const float* a = d.A + (size_t)row * 128;
    float s = 0.f;
    for (int k = 0; k < 128; ++k) s += a[k] * d.W[k * d.Kout + col];
    d.out[(size_t)row * d.Kout + col] = s;
}

// ---------------- merged MFMA GEMMs ----------------
// C[N][256](bf16) = A[N][128](fp32, converted inline) @ W[128][256](wt slice, bf16 W^T)
struct GDesc { const float* A; u16* C; int wslice; int N; int start; };
struct GTab { GDesc d[6]; };

__global__ __launch_bounds__(256) void gemm_all(GTab T, const u16* __restrict__ wt) {
    __shared__ __align__(16) u16 sA[64][136];
    __shared__ __align__(16) u16 sB[64][136];
    int bx = blockIdx.x;
    int mi = 0;
#pragma unroll
    for (int i = 1; i < 6; ++i) if (bx >= T.d[i].start) mi = i;
    GDesc d = T.d[mi];
    int R0 = (bx - d.start) * 64;
    int c0 = blockIdx.y * 64;
    int t = threadIdx.x;
    {   // stage A (fp32 -> bf16): thread t -> tile row t>>2, 32 elems at (t&3)*32
        int r = t >> 2, seg = (t & 3) * 32;
        ushort4 o[8];
        if (R0 + r < d.N) {
            const float4* p = (const float4*)(d.A + (size_t)(R0 + r) * 128 + seg);
#pragma unroll
            for (int q = 0; q < 8; ++q) {
                float4 v = p[q];
                o[q].x = f2bf(v.x); o[q].y = f2bf(v.y); o[q].z = f2bf(v.z); o[q].w = f2bf(v.w);
            }
        } else {
#pragma unroll
            for (int q = 0; q < 8; ++q) o[q] = make_ushort4(0, 0, 0, 0);
        }
        ushort4* qd = (ushort4*)&sA[r][seg];
#pragma unroll
        for (int q = 0; q < 8; ++q) qd[q] = o[q];
        // stage B: rows c0..c0+63 of Bt[256][128] (always in-bounds)
        const uint4* pb = (const uint4*)(wt + (size_t)d.wslice * 32768 + (size_t)(c0 + r) * 128 + seg);
        uint4 b0 = pb[0], b1 = pb[1], b2 = pb[2], b3 = pb[3];
        uint4* qb = (uint4*)&sB[r][seg];
        qb[0] = b0; qb[1] = b1; qb[2] = b2; qb[3] = b3;
    }
    __syncthreads();

    int wave = t >> 6, lane = t & 63;
    int quad = lane >> 4, m = lane & 15;
    f32x4 acc[4] = {};
    const u16* aRow = &sA[wave * 16 + m][0];
#pragma unroll
    for (int k0 = 0; k0 < 128; k0 += 32) {
        s16x8 af = *(const s16x8*)(aRow + k0 + quad * 8);
#pragma unroll
        for (int ct = 0; ct < 4; ++ct) {
            s16x8 bf = *(const s16x8*)(&sB[ct * 16 + m][k0 + quad * 8]);
            acc[ct] = __builtin_amdgcn_mfma_f32_16x16x32_bf16(af, bf, acc[ct], 0, 0, 0);
        }
    }
    // C/D: col = lane&15, row = (lane>>4)*4 + reg
#pragma unroll
    for (int ct = 0; ct < 4; ++ct) {
#pragma unroll
        for (int i = 0; i < 4; ++i) {
            int row = R0 + wave * 16 + quad * 4 + i;
            if (row < d.N) d.C[(size_t)row * 256 + c0 + ct * 16 + m] = f2bf(acc[ct][i]);
        }
    }
}

// ---------------- (row,rel)-segmented CSR build over all 5 relations ----------------
// counters laid out cnt[row*5 + rel] so a row's 5 segments are contiguous in edge order.
struct EdgeP { const int* src[5]; const int* dst[5]; int base[5]; };

__global__ void k_count(EdgeP P, u32* __restrict__ cnt, int E) {
    int r = blockIdx.y;
    int e = blockIdx.x * blockDim.x + threadIdx.x;
    if (e >= E) return;
    atomicAdd(cnt + (size_t)P.dst[r][e] * 5 + r, 1u);
}

__global__ void k_scan1(const u32* __restrict__ cnt, u32* __restrict__ off,
                        u32* __restrict__ bsum, int nblk) {
    int b = blockIdx.x, t = threadIdx.x;
    size_t base = (size_t)b * 1024 + t * 4;
    u32 v0 = cnt[base], v1 = cnt[base + 1], v2 = cnt[base + 2], v3 = cnt[base + 3];
    u32 tsum = v0 + v1 + v2 + v3;
    __shared__ u32 s[256];
    u32 x = tsum;
    s[t] = x; __syncthreads();
    for (int ofs = 1; ofs < 256; ofs <<= 1) {
        u32 y = (t >= ofs) ? s[t - ofs] : 0u;
        __syncthreads();
        x += y; s[t] = x;
        __syncthreads();
    }
    u32 ex = x - tsum;
    off[base] = ex; off[base + 1] = ex + v0; off[base + 2] = ex + v0 + v1; off[base + 3] = ex + v0 + v1 + v2;
    if (t == 255) bsum[b] = x;
}

// single-block scan of nblk block sums (handles nblk in chunks of 512)
__global__ void k_scan2(u32* __restrict__ bsum, int nblk) {
    __shared__ u32 s[512];
    __shared__ u32 carry_s;
    int t = threadIdx.x;
    if (t == 0) carry_s = 0;
    __syncthreads();
    for (int c0 = 0; c0 < nblk; c0 += 512) {
        int i = c0 + t;
        u32 v = (i < nblk) ? bsum[i] : 0u;
        u32 x = v;
        s[t] = x; __syncthreads();
        for (int ofs = 1; ofs < 512; ofs <<= 1) {
            u32 y = (t >= ofs) ? s[t - ofs] : 0u;
            __syncthreads();
            x += y; s[t] = x;
            __syncthreads();
        }
        u32 carry = carry_s;
        if (i < nblk) bsum[i] = x - v + carry;
        __syncthreads();
        if (t == 511) carry_s = carry + x;
        __syncthreads();
    }
}

__global__ void k_scan3(u32* __restrict__ off, const u32* __restrict__ bsum, int nblk) {
    int b = blockIdx.x, t = threadIdx.x;
    u32 add = bsum[b];
    size_t base = (size_t)b * 1024 + t * 4;
    off[base] += add; off[base + 1] += add; off[base + 2] += add; off[base + 3] += add;
}

// payload = base[rel] + src  (rel is implied by segment position — no tag bits)
__global__ void k_fill(EdgeP P, const u32* __restrict__ off, u32* __restrict__ cur,
                       u32* __restrict__ epay, int E) {
    int r = blockIdx.y;
    int e = blockIdx.x * blockDim.x + threadIdx.x;
    if (e >= E) return;
    int d = P.dst[r][e];
    size_t slot = (size_t)d * 5 + r;
    u32 pos = off[slot] + atomicAdd(cur + slot, 1u);
    epay[pos] = (u32)(P.base[r] + P.src[r][e]);
}

// ---------------- fused gather: denominators + weighted gather + residual + ReLU + LN --------
// e-values are O(1) (inputs ~N(0,1), weights 0.05), so exp without max-shift is safe;
// softmax is shift-invariant so the result matches the reference.
// Edge cache: first CAP edges' payload+rel (pc) and exp-weight (wc) live in VGPRs.
// Both passes run in chunks of CH=4 with ONE wave-uniform guard per chunk and a
// branchless interior (invalid slots clamp to the last valid edge, weight forced to 0)
// so each chunk's 4 loads issue back-to-back (MLP), never out of bounds.
__global__ __launch_bounds__(256) void k_gather(
        const u32* __restrict__ offs, const u32* __restrict__ epay,
        const float4* __restrict__ as4, const float* __restrict__ a_d,
        const u16* __restrict__ hs, const u16* __restrict__ resb,
        const float* __restrict__ bias_sum,
        const float* __restrict__ gamma, const float* __restrict__ beta,
        float* __restrict__ out, int NJ) {
    int row = blockIdx.x * 4 + (threadIdx.x >> 6);
    int lane = threadIdx.x & 63;
    if (row >= NJ) return;

    // hoisted epilogue loads — independent, hide under the whole gather
    ushort4 rr = *(const ushort4*)(resb + (size_t)row * 256 + lane * 4);
    float4 bb = *(const float4*)(bias_sum + lane * 4);
    int c = lane * 4;
    float4 g = *(const float4*)(gamma + c);
    float4 be = *(const float4*)(beta + c);

    // per-row, per-lane head-selected a_d for all 5 relations
    const float4* adp = (const float4*)(a_d + (size_t)row * 20);
    float ad0 = pick_head(adp[0], lane), ad1 = pick_head(adp[1], lane),
          ad2 = pick_head(adp[2], lane), ad3 = pick_head(adp[3], lane),
          ad4 = pick_head(adp[4], lane);

    const u32* op = offs + (size_t)row * 5;
    u32 o0 = op[0], o1 = op[1], o2 = op[2], o3 = op[3], o4 = op[4], o5 = op[5];

    constexpr int CAP = 16;
    constexpr int CH = 4;
    u32 pc[CAP];     // payload | rel<<24
    float wc[CAP];   // exp-weight (0 for invalid slots)
    u32 deg = o5 - o0;

    // ---- pass 1: weights + per-relation denominators ----
    float d0 = 0.f, d1 = 0.f, d2 = 0.f, d3 = 0.f, d4 = 0.f;
#pragma unroll
    for (int cb = 0; cb < CAP; cb += CH) {
        if ((u32)cb < deg) {                      // wave-uniform guard (1 per chunk)
            u32 ee[CH], pl[CH];
#pragma unroll
            for (int j = 0; j < CH; ++j) {        // branchless: clamp to last valid edge
                u32 i = (u32)(cb + j);
                u32 ie = (i < deg) ? i : deg - 1;
                ee[j] = o0 + ie;
                pl[j] = epay[ee[j]];
            }
#pragma unroll
            for (int j = 0; j < CH; ++j) {
                u32 e = ee[j], p = pl[j];
                int rel = (int)(e >= o1) + (int)(e >= o2) + (int)(e >= o3) + (int)(e >= o4);
                float4 asv = as4[p];
                float x = pick_head(asv, lane) + sel5(ad0, ad1, ad2, ad3, ad4, rel);
                x = x > 0.f ? x : 0.2f * x;
                bool valid = (u32)(cb + j) < deg;
                float w = valid ? __expf(x) : 0.f;
                pc[cb + j] = p | ((u32)rel << 24);
                wc[cb + j] = w;
                d0 += (rel == 0) ? w : 0.f; d1 += (rel == 1) ? w : 0.f; d2 += (rel == 2) ? w : 0.f;
                d3 += (rel == 3) ? w : 0.f; d4 += (rel == 4) ? w : 0.f;
            }
        }
    }
    for (u32 e = o0 + (u32)(deg < (u32)CAP ? deg : (u32)CAP); e < o5; ++e) {   // tail (deg > CAP)
        u32 p = epay[e];
        int rel = (int)(e >= o1) + (int)(e >= o2) + (int)(e >= o3) + (int)(e >= o4);
        float4 asv = as4[p];
        float x = pick_head(asv, lane) + sel5(ad0, ad1, ad2, ad3, ad4, rel);
        x = x > 0.f ? x : 0.2f * x;
        float w = __expf(x);
        d0 += (rel == 0) ? w : 0.f; d1 += (rel == 1) ? w : 0.f; d2 += (rel == 2) ? w : 0.f;
        d3 += (rel == 3) ? w : 0.f; d4 += (rel == 4) ? w : 0.f;
    }
    float iv0 = 1.f / (d0 + 1e-16f), iv1 = 1.f / (d1 + 1e-16f), iv2 = 1.f / (d2 + 1e-16f),
          iv3 = 1.f / (d3 + 1e-16f), iv4 = 1.f / (d4 + 1e-16f);

    // ---- pass 2: weighted hs gather (cached edges: no epay/as4 reloads, no exp) ----
    float a0 = 0.f, a1 = 0.f, a2 = 0.f, a3 = 0.f;
#pragma unroll
    for (int cb = 0; cb < CAP; cb += CH) {
        if ((u32)cb < deg) {                      // wave-uniform guard
            ushort4 hv[CH];
            float w[CH];
#pragma unroll
            for (int j = 0; j < CH; ++j) {        // branchless interior: wc==0 for pads
                u32 p = pc[cb + j];
                hv[j] = *(const ushort4*)(hs + (size_t)(p & 0xFFFFFFu) * 256 + lane * 4);
                w[j] = wc[cb + j] * sel5(iv0, iv1, iv2, iv3, iv4, (int)(p >> 24));
            }
#pragma unroll
            for (int j = 0; j < CH; ++j) {
                a0 += w[j] * bf2f(hv[j].x); a1 += w[j] * bf2f(hv[j].y);
                a2 += w[j] * bf2f(hv[j].z); a3 += w[j] * bf2f(hv[j].w);
            }
        }
    }
    for (u32 e = o0 + (u32)(deg < (u32)CAP ? deg : (u32)CAP); e < o5; ++e) {   // tail recompute
        u32 p = epay[e];
        int rel = (int)(e >= o1) + (int)(e >= o2) + (int)(e >= o3) + (int)(e >= o4);
        float4 asv = as4[p];
        float x = pick_head(asv, lane) + sel5(ad0, ad1, ad2, ad3, ad4, rel);
        x = x > 0.f ? x : 0.2f * x;
        float w = __expf(x) * sel5(iv0, iv1, iv2, iv3, iv4, rel);
        ushort4 hv = *(const ushort4*)(hs + (size_t)p * 256 + lane * 4);
        a0 += w * bf2f(hv.x); a1 += w * bf2f(hv.y);
        a2 += w * bf2f(hv.z); a3 += w * bf2f(hv.w);
    }

    float h0 = fmaxf(a0 + bf2f(rr.x) + bb.x, 0.f);
    float h1 = fmaxf(a1 + bf2f(rr.y) + bb.y, 0.f);
    float h2 = fmaxf(a2 + bf2f(rr.z) + bb.z, 0.f);
    float h3 = fmaxf(a3 + bf2f(rr.w) + bb.w, 0.f);
    float s = h0 + h1 + h2 + h3;
    float s2 = h0 * h0 + h1 * h1 + h2 * h2 + h3 * h3;
    for (int o = 32; o; o >>= 1) {
        s += __shfl_xor(s, o);
        s2 += __shfl_xor(s2, o);
    }
    float mu = s * (1.f / 256.f);
    float var = s2 * (1.f / 256.f) - mu * mu;
    float rs = rsqrtf(var + 1e-5f);
    float4 o;
    o.x = (h0 - mu) * rs * g.x + be.x;
    o.y = (h1 - mu) * rs * g.y + be.y;
    o.z = (h2 - mu) * rs * g.z + be.z;
    o.w = (h3 - mu) * rs * g.w + be.w;
    *(float4*)(out + (size_t)row * 256 + c) = o;
}

// ---------------------------------------------------------------------------
static size_t align256(size_t x) { return (x + 255) & ~(size_t)255; }

extern "C" void kernel_launch(void* const* d_in, const int* in_sizes, int n_in,
                              void* d_out, int out_size, void* d_ws, size_t ws_size,
                              hipStream_t stream) {
    float* out = (float*)d_out;

    int NJ = in_sizes[0] / 128, NS = in_sizes[1] / 128, NM = in_sizes[2] / 128, NR = in_sizes[3] / 128;
    int E = in_sizes[4];
    bool cfg_ok = (n_in >= 21) && (out_size == NJ * 256)
        && (in_sizes[14] == 5 * 128 * 256) && (in_sizes[18] == 128 * 256)
        && (in_sizes[19] == 256) && (in_sizes[20] == 256);
    if (!cfg_ok) { probe_mark<<<8, 256, 0, stream>>>(out, 2048, 1000000.0f); return; }

    const float* x_job = (const float*)d_in[0];
    const float* x_st  = (const float*)d_in[1];
    const float* x_ma  = (const float*)d_in[2];
    const float* x_ro  = (const float*)d_in[3];
    EdgeP EP;
    EP.src[0] = (const int*)d_in[4];  EP.dst[0] = (const int*)d_in[5];
    EP.src[1] = (const int*)d_in[6];  EP.dst[1] = (const int*)d_in[7];
    EP.src[2] = (const int*)d_in[8];  EP.dst[2] = (const int*)d_in[9];
    EP.src[3] = (const int*)d_in[10]; EP.dst[3] = (const int*)d_in[11];
    EP.src[4] = (const int*)d_in[12]; EP.dst[4] = (const int*)d_in[13];
    EP.base[0] = 0; EP.base[1] = NS; EP.base[2] = 2 * NS;
    EP.base[3] = 2 * NS + NM; EP.base[4] = 2 * NS + 2 * NM;
    const float* Ws      = (const float*)d_in[14];
    const float* att_src = (const float*)d_in[15];
    const float* att_dst = (const float*)d_in[16];
    const float* biases  = (const float*)d_in[17];
    const float* W_res   = (const float*)d_in[18];
    const float* gamma   = (const float*)d_in[19];
    const float* beta    = (const float*)d_in[20];

    // (row,rel)-segmented CSR: 5*NJ counters, padded to scan granularity (1024)
    int nseg = 5 * NJ;
    int nblk = (nseg + 1023) / 1024;
    int NPAD = nblk * 1024;
    int TOT = 2 * NS + 2 * NM + NR;   // concatenated source-node count

    // --- workspace layout ---
    char* base = (char*)d_ws;
    size_t ob = 0;
    float*  w_d_all  = (float*)(base + ob);  ob += align256(128 * 20 * 4);
    float*  w_s_cat  = (float*)(base + ob);  ob += align256(5 * 128 * 4 * 4);
    float*  bias_sum = (float*)(base + ob);  ob += align256(256 * 4);
    float*  a_d      = (float*)(base + ob);  ob += align256((size_t)NJ * 20 * 4);
    float*  as_cat   = (float*)(base + ob);  ob += align256((size_t)TOT * 4 * 4);
    u16*    wt       = (u16*)(base + ob);    ob += align256((size_t)6 * 256 * 128 * 2);
    u16*    resb     = (u16*)(base + ob);    ob += align256((size_t)NJ * 256 * 2);
    u16*    hs_cat   = (u16*)(base + ob);    ob += align256((size_t)TOT * 256 * 2);
    u32*    cnt      = (u32*)(base + ob);    ob += align256((size_t)NPAD * 4);
    u32*    cur      = (u32*)(base + ob);    ob += align256((size_t)NPAD * 4);
    u32*    offs     = (u32*)(base + ob);    ob += align256((size_t)NPAD * 4);
    u32*    bsum     = (u32*)(base + ob);    ob += align256((size_t)nblk * 4);
    u32*    epay     = (u32*)(base + ob);    ob += align256((size_t)5 * E * 4);

    if (ws_size < ob) { probe_mark<<<8, 256, 0, stream>>>(out, 2048, 500000.0f); return; }

    // --- zero cnt+cur in one launch (contiguous) ---
    int zc = 2 * NPAD;
    zero_fill<<<(zc + 255) / 256, 256, 0, stream>>>(cnt, zc);

    cvt_weights<<<(6 * 256 * 128 + 255) / 256, 256, 0, stream>>>(Ws, W_res, wt);
    prep_kernel<<<6, 256, 0, stream>>>(Ws, att_src, att_dst, biases,
                                       w_d_all, w_s_cat, bias_sum);

    // --- merged skinny GEMMs (a_d: NJ x 20, a_s: per-relation N x 4 into as_cat) ---
    STab ST;
    int st = 0;
    ST.d[0] = {x_job, w_d_all,           a_d,                             NJ, 20, st}; st += NJ * 20;
    ST.d[1] = {x_st,  w_s_cat + 0 * 512, as_cat + (size_t)EP.base[0] * 4, NS, 4, st}; st += NS * 4;
    ST.d[2] = {x_st,  w_s_cat + 1 * 512, as_cat + (size_t)EP.base[1] * 4, NS, 4, st}; st += NS * 4;
    ST.d[3] = {x_ma,  w_s_cat + 2 * 512, as_cat + (size_t)EP.base[2] * 4, NM, 4, st}; st += NM * 4;
    ST.d[4] = {x_ma,  w_s_cat + 3 * 512, as_cat + (size_t)EP.base[3] * 4, NM, 4, st}; st += NM * 4;
    ST.d[5] = {x_ro,  w_s_cat + 4 * 512, as_cat + (size_t)EP.base[4] * 4, NR, 4, st}; st += NR * 4;
    ST.total = st;
    skinny_all<<<(ST.total + 255) / 256, 256, 0, stream>>>(ST);

    // --- merged MFMA GEMMs (6 matrices, one launch); hs slices concatenated by gsrc ---
    int tJ = (NJ + 63) / 64, tS = (NS + 63) / 64, tM = (NM + 63) / 64, tR = (NR + 63) / 64;
    GTab GT;
    int gs = 0;
    GT.d[0] = {x_job, resb,                               5, NJ, gs}; gs += tJ;
    GT.d[1] = {x_st,  hs_cat + (size_t)EP.base[0] * 256,  0, NS, gs}; gs += tS;
    GT.d[2] = {x_st,  hs_cat + (size_t)EP.base[1] * 256,  1, NS, gs}; gs += tS;
    GT.d[3] = {x_ma,  hs_cat + (size_t)EP.base[2] * 256,  2, NM, gs}; gs += tM;
    GT.d[4] = {x_ma,  hs_cat + (size_t)EP.base[3] * 256,  3, NM, gs}; gs += tM;
    GT.d[5] = {x_ro,  hs_cat + (size_t)EP.base[4] * 256,  4, NR, gs}; gs += tR;
    gemm_all<<<dim3(gs, 4), 256, 0, stream>>>(GT, wt);

    // --- (row,rel)-segmented CSR build ---
    k_count<<<dim3((E + 255) / 256, 5), 256, 0, stream>>>(EP, cnt, E);
    k_scan1<<<nblk, 256, 0, stream>>>(cnt, offs, bsum, nblk);
    k_scan2<<<1, 512, 0, stream>>>(bsum, nblk);
    k_scan3<<<nblk, 256, 0, stream>>>(offs, bsum, nblk);
    k_fill<<<dim3((E + 255) / 256, 5), 256, 0, stream>>>(EP, offs, cur, epay, E);

    // --- fused denominators + gather + residual + ReLU + LN ---
    k_gather<<<(NJ + 3) / 4, 256, 0, stream>>>(offs, epay, (const float4*)as_cat,
                                               a_d, hs_cat, resb, bias_sum,
                                               gamma, beta, out, NJ);
}

// Round 6
// 613.473 us; speedup vs baseline: 1.0623x; 1.0623x over previous
//
#include <hip/hip_runtime.h>

typedef unsigned short u16;
typedef unsigned int u32;
typedef __attribute__((ext_vector_type(8))) short s16x8;   // 8 bf16 (4 VGPRs)
typedef __attribute__((ext_vector_type(4))) float f32x4;

__device__ __forceinline__ float bf2f(u16 u) { return __uint_as_float(((u32)u) << 16); }
__device__ __forceinline__ u16 f2bf(float f) {
    u32 b = __float_as_uint(f);
    b += 0x7fffu + ((b >> 16) & 1u);
    return (u16)(b >> 16);
}

__global__ void probe_mark(float* __restrict__ out, int n, float val) {
    int i = blockIdx.x * blockDim.x + threadIdx.x;
    if (i < n) out[i] = val;
}

// ---------------- small prep ----------------
__global__ void zero_fill(u32* __restrict__ p, int n) {
    int i = blockIdx.x * blockDim.x + threadIdx.x;
    if (i < n) p[i] = 0u;
}

// wt[(w*256+c)*128+k] = bf16( w<5 ? Ws[w][k][c] : W_res[k][c] )   (W^T, bf16)
__global__ void cvt_weights(const float* __restrict__ Ws, const float* __restrict__ W_res,
                            u16* __restrict__ wt) {
    int i = blockIdx.x * blockDim.x + threadIdx.x;
    if (i >= 6 * 256 * 128) return;
    int k = i & 127;
    int c = (i >> 7) & 255;
    int w = i >> 15;
    float v = (w < 5) ? Ws[(size_t)w * 32768 + k * 256 + c] : W_res[k * 256 + c];
    wt[i] = f2bf(v);
}

// w_d_all[k][rel*4+h] = sum_c W[k][h*64+c]*att_dst[rel][h][c]
// w_s_cat[rel][k][h]  = sum_c W[k][h*64+c]*att_src[rel][h][c]
__global__ void prep_kernel(const float* __restrict__ Ws, const float* __restrict__ att_src,
                            const float* __restrict__ att_dst, const float* __restrict__ biases,
                            float* __restrict__ w_d_all, float* __restrict__ w_s_cat,
                            float* __restrict__ bias_sum) {
    int b = blockIdx.x;
    if (b < 5) {
        int k = threadIdx.x;
        if (k >= 128) return;
        const float* Wr = Ws + (size_t)b * 128 * 256 + (size_t)k * 256;
        for (int h = 0; h < 4; ++h) {
            float ss = 0.f, sd = 0.f;
            for (int c = 0; c < 64; ++c) {
                float w = Wr[h * 64 + c];
                ss += w * att_src[(b * 4 + h) * 64 + c];
                sd += w * att_dst[(b * 4 + h) * 64 + c];
            }
            w_d_all[k * 20 + b * 4 + h] = sd;
            w_s_cat[b * 512 + k * 4 + h] = ss;
        }
    } else if (threadIdx.x < 256) {
        float s = 0.f;
        for (int r = 0; r < 5; ++r) s += biases[r * 256 + threadIdx.x];
        bias_sum[threadIdx.x] = s;
    }
}

// ---------------- merged skinny GEMMs (a_s / a_d projections) ----------------
struct SDesc { const float* A; const float* W; float* out; int N; int Kout; int start; };
struct STab { SDesc d[6]; int total; };

__global__ void skinny_all(STab T) {
    int idx = blockIdx.x * blockDim.x + threadIdx.x;
    if (idx >= T.total) return;
    int mi = 0;
#pragma unroll
    for (int i = 1; i < 6; ++i) if (idx >= T.d[i].start) mi = i;
    SDesc d = T.d[mi];
    int local = idx - d.start;
    int row = local / d.Kout, col = local - row * d.Kout;
    const float* a = d.A + (size_t)row * 128;
    float s = 0.f;
    for (int k = 0; k < 128; ++k) s += a[k] * d.W[k * d.Kout + col];
    d.out[(size_t)row * d.Kout + col] = s;
}

// ---------------- merged MFMA GEMMs ----------------
// C[N][256](bf16) = A[N][128](fp32, converted inline) @ W[128][256](wt slice, bf16 W^T)
struct GDesc { const float* A; u16* C; int wslice; int N; int start; };
struct GTab { GDesc d[6]; };

__global__ __launch_bounds__(256) void gemm_all(GTab T, const u16* __restrict__ wt) {
    __shared__ __align__(16) u16 sA[64][136];
    __shared__ __align__(16) u16 sB[64][136];
    int bx = blockIdx.x;
    int mi = 0;
#pragma unroll
    for (int i = 1; i < 6; ++i) if (bx >= T.d[i].start) mi = i;
    GDesc d = T.d[mi];
    int R0 = (bx - d.start) * 64;
    int c0 = blockIdx.y * 64;
    int t = threadIdx.x;
    {   // stage A (fp32 -> bf16): thread t -> tile row t>>2, 32 elems at (t&3)*32
        int r = t >> 2, seg = (t & 3) * 32;
        ushort4 o[8];
        if (R0 + r < d.N) {
            const float4* p = (const float4*)(d.A + (size_t)(R0 + r) * 128 + seg);
#pragma unroll
            for (int q = 0; q < 8; ++q) {
                float4 v = p[q];
                o[q].x = f2bf(v.x); o[q].y = f2bf(v.y); o[q].z = f2bf(v.z); o[q].w = f2bf(v.w);
            }
        } else {
#pragma unroll
            for (int q = 0; q < 8; ++q) o[q] = make_ushort4(0, 0, 0, 0);
        }
        ushort4* qd = (ushort4*)&sA[r][seg];
#pragma unroll
        for (int q = 0; q < 8; ++q) qd[q] = o[q];
        // stage B: rows c0..c0+63 of Bt[256][128] (always in-bounds)
        const uint4* pb = (const uint4*)(wt + (size_t)d.wslice * 32768 + (size_t)(c0 + r) * 128 + seg);
        uint4 b0 = pb[0], b1 = pb[1], b2 = pb[2], b3 = pb[3];
        uint4* qb = (uint4*)&sB[r][seg];
        qb[0] = b0; qb[1] = b1; qb[2] = b2; qb[3] = b3;
    }
    __syncthreads();

    int wave = t >> 6, lane = t & 63;
    int quad = lane >> 4, m = lane & 15;
    f32x4 acc[4] = {};
    const u16* aRow = &sA[wave * 16 + m][0];
#pragma unroll
    for (int k0 = 0; k0 < 128; k0 += 32) {
        s16x8 af = *(const s16x8*)(aRow + k0 + quad * 8);
#pragma unroll
        for (int ct = 0; ct < 4; ++ct) {
            s16x8 bf = *(const s16x8*)(&sB[ct * 16 + m][k0 + quad * 8]);
            acc[ct] = __builtin_amdgcn_mfma_f32_16x16x32_bf16(af, bf, acc[ct], 0, 0, 0);
        }
    }
    // C/D: col = lane&15, row = (lane>>4)*4 + reg
#pragma unroll
    for (int ct = 0; ct < 4; ++ct) {
#pragma unroll
        for (int i = 0; i < 4; ++i) {
            int row = R0 + wave * 16 + quad * 4 + i;
            if (row < d.N) d.C[(size_t)row * 256 + c0 + ct * 16 + m] = f2bf(acc[ct][i]);
        }
    }
}

// ---------------- (row,rel)-segmented CSR build over all 5 relations ----------------
// counters laid out cnt[row*5 + rel] so a row's 5 segments are contiguous in edge order.
struct EdgeP { const int* src[5]; const int* dst[5]; int base[5]; };

__global__ void k_count(EdgeP P, u32* __restrict__ cnt, int E) {
    int r = blockIdx.y;
    int e = blockIdx.x * blockDim.x + threadIdx.x;
    if (e >= E) return;
    atomicAdd(cnt + (size_t)P.dst[r][e] * 5 + r, 1u);
}

__global__ void k_scan1(const u32* __restrict__ cnt, u32* __restrict__ off,
                        u32* __restrict__ bsum, int nblk) {
    int b = blockIdx.x, t = threadIdx.x;
    size_t base = (size_t)b * 1024 + t * 4;
    u32 v0 = cnt[base], v1 = cnt[base + 1], v2 = cnt[base + 2], v3 = cnt[base + 3];
    u32 tsum = v0 + v1 + v2 + v3;
    __shared__ u32 s[256];
    u32 x = tsum;
    s[t] = x; __syncthreads();
    for (int ofs = 1; ofs < 256; ofs <<= 1) {
        u32 y = (t >= ofs) ? s[t - ofs] : 0u;
        __syncthreads();
        x += y; s[t] = x;
        __syncthreads();
    }
    u32 ex = x - tsum;
    off[base] = ex; off[base + 1] = ex + v0; off[base + 2] = ex + v0 + v1; off[base + 3] = ex + v0 + v1 + v2;
    if (t == 255) bsum[b] = x;
}

// single-block scan of nblk block sums (handles nblk in chunks of 512)
__global__ void k_scan2(u32* __restrict__ bsum, int nblk) {
    __shared__ u32 s[512];
    __shared__ u32 carry_s;
    int t = threadIdx.x;
    if (t == 0) carry_s = 0;
    __syncthreads();
    for (int c0 = 0; c0 < nblk; c0 += 512) {
        int i = c0 + t;
        u32 v = (i < nblk) ? bsum[i] : 0u;
        u32 x = v;
        s[t] = x; __syncthreads();
        for (int ofs = 1; ofs < 512; ofs <<= 1) {
            u32 y = (t >= ofs) ? s[t - ofs] : 0u;
            __syncthreads();
            x += y; s[t] = x;
            __syncthreads();
        }
        u32 carry = carry_s;
        if (i < nblk) bsum[i] = x - v + carry;
        __syncthreads();
        if (t == 511) carry_s = carry + x;
        __syncthreads();
    }
}

__global__ void k_scan3(u32* __restrict__ off, const u32* __restrict__ bsum, int nblk) {
    int b = blockIdx.x, t = threadIdx.x;
    u32 add = bsum[b];
    size_t base = (size_t)b * 1024 + t * 4;
    off[base] += add; off[base + 1] += add; off[base + 2] += add; off[base + 3] += add;
}

// payload = base[rel] + src  (rel is implied by segment position — no tag bits)
__global__ void k_fill(EdgeP P, const u32* __restrict__ off, u32* __restrict__ cur,
                       u32* __restrict__ epay, int E) {
    int r = blockIdx.y;
    int e = blockIdx.x * blockDim.x + threadIdx.x;
    if (e >= E) return;
    int d = P.dst[r][e];
    size_t slot = (size_t)d * 5 + r;
    u32 pos = off[slot] + atomicAdd(cur + slot, 1u);
    epay[pos] = (u32)(P.base[r] + P.src[r][e]);
}

// ---------------- fused gather (single pass, rel as compile-time constant) --------------
// R5 PMC: VALUBusy=95%, MfmaUtil=0, hbm=27% -> VALU-issue-bound (~200 instrs/edge from
// per-edge rel decode, sel5 chains, 5-way predicated accumulation, 2-pass cache machinery).
// Fix: iterate the 5 (row,rel) segments with rel constant (unrolled), accumulate
// per-relation numerators+denominator, normalize AFTER each segment:
//   out += (sum_e w*h) / (sum_e w)   ==  sum_e (w/d)*h   (algebraically identical).
// ~22 VALU/edge. exp without max-shift validated correct in R5 (absmax 0.03, passed).
__global__ __launch_bounds__(256) void k_gather(
        const u32* __restrict__ offs, const u32* __restrict__ epay,
        const float* __restrict__ as_h,   // as_cat: [gsrc][4 heads], scalar per-head access
        const float* __restrict__ a_d,    // [row][rel*4+h]
        const u16* __restrict__ hs, const u16* __restrict__ resb,
        const float* __restrict__ bias_sum,
        const float* __restrict__ gamma, const float* __restrict__ beta,
        float* __restrict__ out, int NJ) {
    int row = blockIdx.x * 4 + (threadIdx.x >> 6);
    int lane = threadIdx.x & 63;
    if (row >= NJ) return;

    // hoisted epilogue loads — hide under the gather
    ushort4 rr = *(const ushort4*)(resb + (size_t)row * 256 + lane * 4);
    float4 bb = *(const float4*)(bias_sum + lane * 4);
    int c = lane * 4;
    float4 g = *(const float4*)(gamma + c);
    float4 be = *(const float4*)(beta + c);

    int hd = lane >> 4;                        // this lane's head (0..3)
    u32 hoff = (u32)(lane << 2);               // u16-elem offset within an hs row

    // per-row, per-head a_d for all 5 relations (scalar broadcast loads)
    const float* adb = a_d + (size_t)row * 20 + hd;
    float adx[5] = { adb[0], adb[4], adb[8], adb[12], adb[16] };

    const u32* op = offs + (size_t)row * 5;
    u32 o[6];
#pragma unroll
    for (int i = 0; i < 6; ++i) o[i] = op[i];

    float a0 = 0.f, a1 = 0.f, a2 = 0.f, a3 = 0.f;
#pragma unroll
    for (int r = 0; r < 5; ++r) {              // rel is a compile-time constant
        float adr = adx[r];
        float n0 = 0.f, n1 = 0.f, n2 = 0.f, n3 = 0.f, dsum = 0.f;
        for (u32 e = o[r]; e < o[r + 1]; ++e) {
            u32 p = epay[e];
            float x = as_h[p * 4 + (u32)hd] + adr;
            x = x > 0.f ? x : 0.2f * x;
            float w = __expf(x);
            dsum += w;
            ushort4 hv = *(const ushort4*)(hs + ((p << 8) + hoff));
            n0 += w * bf2f(hv.x); n1 += w * bf2f(hv.y);
            n2 += w * bf2f(hv.z); n3 += w * bf2f(hv.w);
        }
        float iv = 1.f / (dsum + 1e-16f);      // empty segment: 0 * 1e16 = 0, safe
        a0 += n0 * iv; a1 += n1 * iv; a2 += n2 * iv; a3 += n3 * iv;
    }

    float h0 = fmaxf(a0 + bf2f(rr.x) + bb.x, 0.f);
    float h1 = fmaxf(a1 + bf2f(rr.y) + bb.y, 0.f);
    float h2 = fmaxf(a2 + bf2f(rr.z) + bb.z, 0.f);
    float h3 = fmaxf(a3 + bf2f(rr.w) + bb.w, 0.f);
    float s = h0 + h1 + h2 + h3;
    float s2 = h0 * h0 + h1 * h1 + h2 * h2 + h3 * h3;
    for (int o2 = 32; o2; o2 >>= 1) {
        s += __shfl_xor(s, o2);
        s2 += __shfl_xor(s2, o2);
    }
    float mu = s * (1.f / 256.f);
    float var = s2 * (1.f / 256.f) - mu * mu;
    float rs = rsqrtf(var + 1e-5f);
    float4 o4;
    o4.x = (h0 - mu) * rs * g.x + be.x;
    o4.y = (h1 - mu) * rs * g.y + be.y;
    o4.z = (h2 - mu) * rs * g.z + be.z;
    o4.w = (h3 - mu) * rs * g.w + be.w;
    *(float4*)(out + (size_t)row * 256 + c) = o4;
}

// ---------------------------------------------------------------------------
static size_t align256(size_t x) { return (x + 255) & ~(size_t)255; }

extern "C" void kernel_launch(void* const* d_in, const int* in_sizes, int n_in,
                              void* d_out, int out_size, void* d_ws, size_t ws_size,
                              hipStream_t stream) {
    float* out = (float*)d_out;

    int NJ = in_sizes[0] / 128, NS = in_sizes[1] / 128, NM = in_sizes[2] / 128, NR = in_sizes[3] / 128;
    int E = in_sizes[4];
    bool cfg_ok = (n_in >= 21) && (out_size == NJ * 256)
        && (in_sizes[14] == 5 * 128 * 256) && (in_sizes[18] == 128 * 256)
        && (in_sizes[19] == 256) && (in_sizes[20] == 256);
    if (!cfg_ok) { probe_mark<<<8, 256, 0, stream>>>(out, 2048, 1000000.0f); return; }

    const float* x_job = (const float*)d_in[0];
    const float* x_st  = (const float*)d_in[1];
    const float* x_ma  = (const float*)d_in[2];
    const float* x_ro  = (const float*)d_in[3];
    EdgeP EP;
    EP.src[0] = (const int*)d_in[4];  EP.dst[0] = (const int*)d_in[5];
    EP.src[1] = (const int*)d_in[6];  EP.dst[1] = (const int*)d_in[7];
    EP.src[2] = (const int*)d_in[8];  EP.dst[2] = (const int*)d_in[9];
    EP.src[3] = (const int*)d_in[10]; EP.dst[3] = (const int*)d_in[11];
    EP.src[4] = (const int*)d_in[12]; EP.dst[4] = (const int*)d_in[13];
    EP.base[0] = 0; EP.base[1] = NS; EP.base[2] = 2 * NS;
    EP.base[3] = 2 * NS + NM; EP.base[4] = 2 * NS + 2 * NM;
    const float* Ws      = (const float*)d_in[14];
    const float* att_src = (const float*)d_in[15];
    const float* att_dst = (const float*)d_in[16];
    const float* biases  = (const float*)d_in[17];
    const float* W_res   = (const float*)d_in[18];
    const float* gamma   = (const float*)d_in[19];
    const float* beta    = (const float*)d_in[20];

    // (row,rel)-segmented CSR: 5*NJ counters, padded to scan granularity (1024)
    int nseg = 5 * NJ;
    int nblk = (nseg + 1023) / 1024;
    int NPAD = nblk * 1024;
    int TOT = 2 * NS + 2 * NM + NR;   // concatenated source-node count

    // --- workspace layout ---
    char* base = (char*)d_ws;
    size_t ob = 0;
    float*  w_d_all  = (float*)(base + ob);  ob += align256(128 * 20 * 4);
    float*  w_s_cat  = (float*)(base + ob);  ob += align256(5 * 128 * 4 * 4);
    float*  bias_sum = (float*)(base + ob);  ob += align256(256 * 4);
    float*  a_d      = (float*)(base + ob);  ob += align256((size_t)NJ * 20 * 4);
    float*  as_cat   = (float*)(base + ob);  ob += align256((size_t)TOT * 4 * 4);
    u16*    wt       = (u16*)(base + ob);    ob += align256((size_t)6 * 256 * 128 * 2);
    u16*    resb     = (u16*)(base + ob);    ob += align256((size_t)NJ * 256 * 2);
    u16*    hs_cat   = (u16*)(base + ob);    ob += align256((size_t)TOT * 256 * 2);
    u32*    cnt      = (u32*)(base + ob);    ob += align256((size_t)NPAD * 4);
    u32*    cur      = (u32*)(base + ob);    ob += align256((size_t)NPAD * 4);
    u32*    offs     = (u32*)(base + ob);    ob += align256((size_t)NPAD * 4);
    u32*    bsum     = (u32*)(base + ob);    ob += align256((size_t)nblk * 4);
    u32*    epay     = (u32*)(base + ob);    ob += align256((size_t)5 * E * 4);

    if (ws_size < ob) { probe_mark<<<8, 256, 0, stream>>>(out, 2048, 500000.0f); return; }

    // --- zero cnt+cur in one launch (contiguous) ---
    int zc = 2 * NPAD;
    zero_fill<<<(zc + 255) / 256, 256, 0, stream>>>(cnt, zc);

    cvt_weights<<<(6 * 256 * 128 + 255) / 256, 256, 0, stream>>>(Ws, W_res, wt);
    prep_kernel<<<6, 256, 0, stream>>>(Ws, att_src, att_dst, biases,
                                       w_d_all, w_s_cat, bias_sum);

    // --- merged skinny GEMMs (a_d: NJ x 20, a_s: per-relation N x 4 into as_cat) ---
    STab ST;
    int st = 0;
    ST.d[0] = {x_job, w_d_all,           a_d,                             NJ, 20, st}; st += NJ * 20;
    ST.d[1] = {x_st,  w_s_cat + 0 * 512, as_cat + (size_t)EP.base[0] * 4, NS, 4, st}; st += NS * 4;
    ST.d[2] = {x_st,  w_s_cat + 1 * 512, as_cat + (size_t)EP.base[1] * 4, NS, 4, st}; st += NS * 4;
    ST.d[3] = {x_ma,  w_s_cat + 2 * 512, as_cat + (size_t)EP.base[2] * 4, NM, 4, st}; st += NM * 4;
    ST.d[4] = {x_ma,  w_s_cat + 3 * 512, as_cat + (size_t)EP.base[3] * 4, NM, 4, st}; st += NM * 4;
    ST.d[5] = {x_ro,  w_s_cat + 4 * 512, as_cat + (size_t)EP.base[4] * 4, NR, 4, st}; st += NR * 4;
    ST.total = st;
    skinny_all<<<(ST.total + 255) / 256, 256, 0, stream>>>(ST);

    // --- merged MFMA GEMMs (6 matrices, one launch); hs slices concatenated by gsrc ---
    int tJ = (NJ + 63) / 64, tS = (NS + 63) / 64, tM = (NM + 63) / 64, tR = (NR + 63) / 64;
    GTab GT;
    int gs = 0;
    GT.d[0] = {x_job, resb,                               5, NJ, gs}; gs += tJ;
    GT.d[1] = {x_st,  hs_cat + (size_t)EP.base[0] * 256,  0, NS, gs}; gs += tS;
    GT.d[2] = {x_st,  hs_cat + (size_t)EP.base[1] * 256,  1, NS, gs}; gs += tS;
    GT.d[3] = {x_ma,  hs_cat + (size_t)EP.base[2] * 256,  2, NM, gs}; gs += tM;
    GT.d[4] = {x_ma,  hs_cat + (size_t)EP.base[3] * 256,  3, NM, gs}; gs += tM;
    GT.d[5] = {x_ro,  hs_cat + (size_t)EP.base[4] * 256,  4, NR, gs}; gs += tR;
    gemm_all<<<dim3(gs, 4), 256, 0, stream>>>(GT, wt);

    // --- (row,rel)-segmented CSR build ---
    k_count<<<dim3((E + 255) / 256, 5), 256, 0, stream>>>(EP, cnt, E);
    k_scan1<<<nblk, 256, 0, stream>>>(cnt, offs, bsum, nblk);
    k_scan2<<<1, 512, 0, stream>>>(bsum, nblk);
    k_scan3<<<nblk, 256, 0, stream>>>(offs, bsum, nblk);
    k_fill<<<dim3((E + 255) / 256, 5), 256, 0, stream>>>(EP, offs, cur, epay, E);

    // --- fused denominators + gather + residual + ReLU + LN (single pass) ---
    k_gather<<<(NJ + 3) / 4, 256, 0, stream>>>(offs, epay, as_cat,
                                               a_d, hs_cat, resb, bias_sum,
                                               gamma, beta, out, NJ);
}